// Round 10
// baseline (7619.056 us; speedup 1.0000x reference)
//
#include <hip/hip_runtime.h>

typedef long long i64;

#define NN 65536
#define CC 256
#define EE 262144
#define GG 512
#define PP 128
#define LL 2
#define HH 9
#define EPSf 1e-5f
#define KPAD 192
#define CHG 128            // graphs per chunk
#define CHR (CHG * PP)     // rows per chunk = 16384
#define NCHUNK 4

__device__ __forceinline__ float siluf(float x) { return x / (1.f + __expf(-x)); }

// ---------------- generic f32 GEMM: Co = act(A [+A2]) @ W^T + bias [+Rp] ----------------
// A: [M,K] row-major (lda), W: [Nc,K] row-major, Co: [M,Nc] (ldc). M%128==0, K%32==0.
// A2 (optional, same layout as A) added pre-GEMM; act: 0=none 1=relu (epilogue);
// Rp (optional) residual added in epilogue. Single instantiation to minimize compile size.
__global__ __launch_bounds__(256)
void gemm_k(const float* __restrict__ A, const float* __restrict__ A2, int lda,
            const float* __restrict__ W, const float* __restrict__ bias,
            const float* __restrict__ Rp, int act,
            float* __restrict__ Co, int ldc,
            int M, int Nc, int K,
            i64 aB, i64 wB, i64 bB, i64 cB)
{
    __shared__ float As[32][132];
    __shared__ float Ws[32][132];
    const int tid = threadIdx.x;
    const int tx = tid & 15, ty = tid >> 4;
    const int m0 = blockIdx.x * 128;
    const int n0 = blockIdx.y * 128;
    const int bz = blockIdx.z;
    A += (i64)bz * aB;
    W += (i64)bz * wB;
    const float* bptr = bias ? (bias + (i64)bz * bB) : (const float*)nullptr;
    Co += (i64)bz * cB;

    float acc[8][8];
#pragma unroll
    for (int i = 0; i < 8; i++)
#pragma unroll
        for (int j = 0; j < 8; j++) {
            int n = n0 + tx * 8 + j;
            acc[i][j] = (bptr && n < Nc) ? bptr[n] : 0.f;
        }

    for (int k0 = 0; k0 < K; k0 += 32) {
#pragma unroll
        for (int i = 0; i < 4; ++i) {
            int f = tid + i * 256;
            int row = f >> 3, k4 = f & 7;
            float4 u = *(const float4*)(A + (i64)(m0 + row) * lda + k0 + k4 * 4);
            if (A2) {
                const float4 w2 = *(const float4*)(A2 + (i64)(m0 + row) * lda + k0 + k4 * 4);
                u.x += w2.x; u.y += w2.y; u.z += w2.z; u.w += w2.w;
            }
            As[k4 * 4 + 0][row] = u.x; As[k4 * 4 + 1][row] = u.y;
            As[k4 * 4 + 2][row] = u.z; As[k4 * 4 + 3][row] = u.w;
        }
#pragma unroll
        for (int i = 0; i < 4; ++i) {
            int f = tid + i * 256;
            int row = f >> 3, k4 = f & 7;
            int wr = n0 + row;
            float4 v = make_float4(0.f, 0.f, 0.f, 0.f);
            if (wr < Nc) v = *(const float4*)(W + (i64)wr * K + k0 + k4 * 4);
            Ws[k4 * 4 + 0][row] = v.x; Ws[k4 * 4 + 1][row] = v.y;
            Ws[k4 * 4 + 2][row] = v.z; Ws[k4 * 4 + 3][row] = v.w;
        }
        __syncthreads();
#pragma unroll
        for (int k = 0; k < 32; ++k) {
            float av[8], bv[8];
            *(float4*)&av[0] = *(const float4*)&As[k][ty * 8];
            *(float4*)&av[4] = *(const float4*)&As[k][ty * 8 + 4];
            *(float4*)&bv[0] = *(const float4*)&Ws[k][tx * 8];
            *(float4*)&bv[4] = *(const float4*)&Ws[k][tx * 8 + 4];
#pragma unroll
            for (int i = 0; i < 8; i++)
#pragma unroll
                for (int j = 0; j < 8; j++)
                    acc[i][j] = fmaf(av[i], bv[j], acc[i][j]);
        }
        __syncthreads();
    }
#pragma unroll
    for (int i = 0; i < 8; i++) {
        int m = m0 + ty * 8 + i;
#pragma unroll
        for (int j4 = 0; j4 < 2; j4++) {
            int n = n0 + tx * 8 + j4 * 4;
            if (n >= Nc) continue;
            float4 o;
            float* ov = (float*)&o;
#pragma unroll
            for (int j = 0; j < 4; j++) {
                float v = acc[i][j4 * 4 + j];
                if (act == 1) v = fmaxf(v, 0.f);
                if (Rp) v += Rp[(i64)m * ldc + n + j];
                ov[j] = v;
            }
            *(float4*)(Co + (i64)m * ldc + n) = o;
        }
    }
}

// ---------------- embedding helpers ----------------
__global__ void k_padx(const float* __restrict__ x, float* __restrict__ XP)
{
    i64 total = (i64)CHR * KPAD;
    for (i64 idx = (i64)blockIdx.x * blockDim.x + threadIdx.x; idx < total;
         idx += (i64)gridDim.x * blockDim.x) {
        int k = (int)(idx % KPAD);
        i64 n = idx / KPAD;
        XP[idx] = (k < 173) ? x[n * 173 + k] : 0.f;
    }
}

__global__ void k_padw(const float* __restrict__ nW, const float* __restrict__ nb,
                       float* __restrict__ WP, float* __restrict__ BP)
{
    int idx = blockIdx.x * 256 + threadIdx.x;
    if (idx < 256 * KPAD) {
        int k = idx % KPAD, r = idx / KPAD;
        WP[idx] = (r < 253 && k < 173) ? nW[r * 173 + k] : 0.f;
    }
    if (idx < 256) BP[idx] = (idx < 253) ? nb[idx] : 0.f;
}

__global__ __launch_bounds__(256)
void k_pestat(const float* __restrict__ pe, const float* __restrict__ bw,
              const float* __restrict__ bb, float* __restrict__ peSc, float* __restrict__ peSh)
{
    float s[3] = {0, 0, 0}, q[3] = {0, 0, 0};
    for (int r = threadIdx.x; r < NN; r += 256) {
#pragma unroll
        for (int j = 0; j < 3; j++) {
            float v = pe[(i64)r * 3 + j];
            s[j] += v; q[j] = fmaf(v, v, q[j]);
        }
    }
#pragma unroll
    for (int off = 32; off; off >>= 1) {
#pragma unroll
        for (int j = 0; j < 3; j++) { s[j] += __shfl_down(s[j], off); q[j] += __shfl_down(q[j], off); }
    }
    __shared__ float red[4][6];
    int wave = threadIdx.x >> 6;
    if ((threadIdx.x & 63) == 0) {
#pragma unroll
        for (int j = 0; j < 3; j++) { red[wave][j] = s[j]; red[wave][3 + j] = q[j]; }
    }
    __syncthreads();
    if (threadIdx.x == 0) {
#pragma unroll
        for (int j = 0; j < 3; j++) {
            float ss = red[0][j] + red[1][j] + red[2][j] + red[3][j];
            float qq = red[0][3 + j] + red[1][3 + j] + red[2][3 + j] + red[3][3 + j];
            float m = ss / (float)NN;
            float var = qq / (float)NN - m * m;
            float scv = bw[j] * rsqrtf(var + EPSf);
            peSc[j] = scv; peSh[j] = bb[j] - m * scv;
        }
    }
}

__global__ void k_peapply(const float* __restrict__ pe, const float* __restrict__ peSc,
                          const float* __restrict__ peSh, const float* __restrict__ pW,
                          const float* __restrict__ pb, float* __restrict__ X)
{
    int n = blockIdx.x * 256 + threadIdx.x;
    if (n >= NN) return;
    float v0 = pe[(i64)n * 3 + 0] * peSc[0] + peSh[0];
    float v1 = pe[(i64)n * 3 + 1] * peSc[1] + peSh[1];
    float v2 = pe[(i64)n * 3 + 2] * peSc[2] + peSh[2];
#pragma unroll
    for (int i = 0; i < 3; i++)
        X[(i64)n * CC + 253 + i] = pb[i] + v0 * pW[i * 3 + 0] + v1 * pW[i * 3 + 1] + v2 * pW[i * 3 + 2];
}

// ---------------- GINE gather: agg = segment_sum(relu(X[src]+ea), dst) ----------------
__global__ __launch_bounds__(128)
void k_gather(const float* __restrict__ X, const int* __restrict__ eidx,
              const float* __restrict__ eattr, const float* __restrict__ eW,
              const float* __restrict__ eb, float* __restrict__ out, int g0)
{
    __shared__ float agg[64 * 128];  // 32 KB
    const int ch = blockIdx.x;       // channel half
    const int gl = blockIdx.y;       // graph within chunk
    const int gg = g0 + gl;
    const int cl = threadIdx.x;
    const int c = ch * 128 + cl;
    float ewr[13];
#pragma unroll
    for (int j = 0; j < 13; j++) ewr[j] = eW[c * 13 + j];
    const float ebr = eb[c];
    const int e0 = gg * 512;
#pragma unroll
    for (int half = 0; half < 2; ++half) {
        for (int i = cl; i < 64 * 128; i += 128) agg[i] = 0.f;  // own column only
        const int rlo = half * 64;
        for (int e = e0; e < e0 + 512; ++e) {
            const int d = eidx[EE + e];
            const int r = d - gg * PP - rlo;
            if ((unsigned)r < 64u) {
                const int s = eidx[e];
                const float* ar = eattr + (i64)e * 13;
                float v = ebr;
#pragma unroll
                for (int j = 0; j < 13; j++) v = fmaf(ar[j], ewr[j], v);
                v += X[(i64)s * CC + c];
                agg[r * 128 + cl] += fmaxf(v, 0.f);
            }
        }
        for (int r = 0; r < 64; ++r)
            out[(i64)(gl * PP + rlo + r) * CC + ch * 128 + cl] = agg[r * 128 + cl];
    }
}

// ---------------- mamba pieces (chunk-local) ----------------
__global__ void k_conv(const float* __restrict__ upre, const float* __restrict__ cw,
                       const float* __restrict__ cb, float* __restrict__ out)
{
    i64 total = (i64)CHR * CC;
    for (i64 idx = (i64)blockIdx.x * blockDim.x + threadIdx.x; idx < total;
         idx += (i64)gridDim.x * blockDim.x) {
        int c = (int)(idx & 255);
        i64 n = idx >> 8;
        int t = (int)(n & 127);
        float acc = cb[c];
#pragma unroll
        for (int j = 0; j < 4; j++) {
            int tt = t + j - 3;
            if (tt >= 0) acc = fmaf(cw[c * 4 + j], upre[(n + j - 3) * CC + c], acc);
        }
        out[idx] = siluf(acc);
    }
}

// fused dt-proj + softplus + selective scan; uy: u in, y out (in place). One block per graph.
__global__ __launch_bounds__(256)
void k_scan(float* __restrict__ uy, const float* __restrict__ dtBC,
            const float* __restrict__ dtW, const float* __restrict__ dtb,
            const float* __restrict__ Alog, const float* __restrict__ Dv)
{
    __shared__ float BC[PP][48];
    const int g = blockIdx.x;   // graph within chunk
    const int c = threadIdx.x;
    for (int idx = c; idx < PP * 48; idx += 256) {
        int t = idx / 48, j = idx - t * 48;
        BC[t][j] = dtBC[(i64)(g * PP + t) * 48 + j];
    }
    float Wr[16], Ar[16], s[16];
#pragma unroll
    for (int d = 0; d < 16; ++d) {
        Wr[d] = dtW[c * 16 + d];
        Ar[d] = -__expf(Alog[c * 16 + d]);
        s[d] = 0.f;
    }
    const float bC = dtb[c];
    const float Dp = Dv[c];
    __syncthreads();
    for (int t = 0; t < PP; ++t) {
        const i64 ni = (i64)(g * PP + t) * CC + c;
        const float ut = uy[ni];
        float dtv = bC;
#pragma unroll
        for (int d = 0; d < 16; ++d) dtv = fmaf(BC[t][d], Wr[d], dtv);
        const float dd = fmaxf(dtv, 0.f) + log1pf(__expf(-fabsf(dtv)));  // softplus
        const float du = dd * ut;
        float y = Dp * ut;
#pragma unroll
        for (int d = 0; d < 16; ++d) {
            s[d] = fmaf(__expf(dd * Ar[d]), s[d], du * BC[t][16 + d]);
            y = fmaf(s[d], BC[t][32 + d], y);
        }
        uy[ni] = y;
    }
}

__global__ void k_gate(float* __restrict__ y, const float* __restrict__ z)
{
    i64 total = (i64)CHR * CC;
    for (i64 idx = (i64)blockIdx.x * blockDim.x + threadIdx.x; idx < total;
         idx += (i64)gridDim.x * blockDim.x)
        y[idx] *= siluf(z[idx]);
}

// ---------------- deterministic BN stats ----------------
__global__ __launch_bounds__(256)
void k_statpart(const float* __restrict__ srcA, const float* __restrict__ srcB,
                float* __restrict__ pS, float* __restrict__ pQ)
{
    const int rb = blockIdx.x, which = blockIdx.y;
    const float* src = which ? srcB : srcA;
    const int c = threadIdx.x;
    float s = 0.f, q = 0.f;
    const i64 base = (i64)rb * 256 * CC;
    for (int r = 0; r < 256; ++r) {
        float v = src[base + (i64)r * CC + c];
        s += v; q = fmaf(v, v, q);
    }
    pS[((i64)which * 256 + rb) * 256 + c] = s;
    pQ[((i64)which * 256 + rb) * 256 + c] = q;
}

__global__ void k_statred(const float* __restrict__ pS, const float* __restrict__ pQ,
                          const float* __restrict__ w, const float* __restrict__ b,
                          float* __restrict__ scale, float* __restrict__ shift, float invN)
{
    const int c = threadIdx.x;
    float s = 0.f, q = 0.f;
    for (int rb = 0; rb < 256; ++rb) { s += pS[rb * 256 + c]; q += pQ[rb * 256 + c]; }
    float m = s * invN;
    float var = q * invN - m * m;
    float sc = w[c] * rsqrtf(var + EPSf);
    scale[c] = sc; shift[c] = b[c] - m * sc;
}

__global__ void k_mix(const float* __restrict__ a, const float* __restrict__ bsrc,
                      const float* __restrict__ sc1, const float* __restrict__ sh1,
                      const float* __restrict__ sc2, const float* __restrict__ sh2,
                      float* __restrict__ out)
{
    i64 total = (i64)CHR * CC;
    for (i64 idx = (i64)blockIdx.x * blockDim.x + threadIdx.x; idx < total;
         idx += (i64)gridDim.x * blockDim.x) {
        int c = (int)(idx & 255);
        out[idx] = fmaf(a[idx], sc1[c], sh1[c]) + fmaf(bsrc[idx], sc2[c], sh2[c]);
    }
}

__global__ void k_affine(const float* __restrict__ src, const float* __restrict__ sc,
                         const float* __restrict__ sh, float* __restrict__ out)
{
    i64 total = (i64)NN * CC;
    for (i64 idx = (i64)blockIdx.x * blockDim.x + threadIdx.x; idx < total;
         idx += (i64)gridDim.x * blockDim.x) {
        int c = (int)(idx & 255);
        out[idx] = fmaf(src[idx], sc[c], sh[c]);
    }
}

// ---------------- pooling + heads ----------------
__global__ __launch_bounds__(256)
void k_pool(const float* __restrict__ X, float* __restrict__ pooled)
{
    int g = blockIdx.x, c = threadIdx.x;
    float s = 0.f;
    for (int r = 0; r < PP; ++r) s += X[(i64)(g * PP + r) * CC + c];
    pooled[(i64)g * CC + c] = s;
}

__global__ __launch_bounds__(256)
void k_gstat(const float* __restrict__ pooled, float* __restrict__ gm, float* __restrict__ gr)
{
    int g = blockIdx.x;
    float v = pooled[(i64)g * CC + threadIdx.x];
    float s = v, q = v * v;
#pragma unroll
    for (int off = 32; off; off >>= 1) { s += __shfl_down(s, off); q += __shfl_down(q, off); }
    __shared__ float rs[4], rq[4];
    if ((threadIdx.x & 63) == 0) { rs[threadIdx.x >> 6] = s; rq[threadIdx.x >> 6] = q; }
    __syncthreads();
    if (threadIdx.x == 0) {
        float S = rs[0] + rs[1] + rs[2] + rs[3];
        float Q = rq[0] + rq[1] + rq[2] + rq[3];
        float m = S * (1.f / 256.f);
        float var = Q * (1.f / 256.f) - m * m;
        gm[g] = m; gr[g] = rsqrtf(var + EPSf);
    }
}

__global__ void k_tln(const float* __restrict__ pooled, const float* __restrict__ gm,
                      const float* __restrict__ gr, const float* __restrict__ lw,
                      const float* __restrict__ lb, float* __restrict__ tln)
{
    int hg = blockIdx.x, c = threadIdx.x;
    int h = hg >> 9, g = hg & 511;
    tln[(i64)hg * CC + c] = (pooled[(i64)g * CC + c] - gm[g]) * gr[g] * lw[h * CC + c] + lb[h * CC + c];
}

__global__ __launch_bounds__(256)
void k_hstat(const float* __restrict__ t2b, float* __restrict__ hs, float* __restrict__ hq)
{
    int h = blockIdx.x, c = threadIdx.x;
    float s = 0.f, q = 0.f;
    for (int g = 0; g < GG; ++g) {
        float v = t2b[((i64)h * GG + g) * CC + c];
        s += v; q = fmaf(v, v, q);
    }
    hs[h * CC + c] = s; hq[h * CC + c] = q;
}

__global__ __launch_bounds__(64)
void k_final(const float* __restrict__ t2b, const float* __restrict__ hs,
             const float* __restrict__ hq, const float* __restrict__ bw,
             const float* __restrict__ bb, const float* __restrict__ W2,
             const float* __restrict__ b2, float* __restrict__ out)
{
    int g = blockIdx.x, h = blockIdx.y, j = threadIdx.x;
    float acc = 0.f;
    for (int c = j; c < CC; c += 64) {
        float v = t2b[((i64)h * GG + g) * CC + c];
        float m = hs[h * CC + c] * (1.f / 512.f);
        float var = hq[h * CC + c] * (1.f / 512.f) - m * m;
        float sc = bw[h * CC + c] * rsqrtf(var + EPSf);
        v = (v - m) * sc + bb[h * CC + c];
        v = fmaxf(v, 0.f);
        acc = fmaf(v, W2[h * CC + c], acc);
    }
#pragma unroll
    for (int off = 32; off; off >>= 1) acc += __shfl_down(acc, off);
    if (j == 0) out[(i64)h * GG + g] = acc + b2[h];
}

// ---------------- host ----------------
extern "C" void kernel_launch(void* const* d_in, const int* in_sizes, int n_in,
                              void* d_out, int out_size, void* d_ws, size_t ws_size,
                              hipStream_t stream)
{
    const float* x      = (const float*)d_in[0];
    const float* pe     = (const float*)d_in[1];
    const int*   eidx   = (const int*)d_in[2];
    const float* eattr  = (const float*)d_in[4];
    const float* node_W = (const float*)d_in[5];
    const float* node_b = (const float*)d_in[6];
    const float* pe_bnw = (const float*)d_in[7];
    const float* pe_bnb = (const float*)d_in[8];
    const float* pe_W   = (const float*)d_in[9];
    const float* pe_b   = (const float*)d_in[10];
    const float* edge_W = (const float*)d_in[11];
    const float* edge_b = (const float*)d_in[12];
    const float* gW1 = (const float*)d_in[13];
    const float* gb1 = (const float*)d_in[14];
    const float* gW2 = (const float*)d_in[15];
    const float* gb2 = (const float*)d_in[16];
    const float* m_inW = (const float*)d_in[17];
    const float* m_cW  = (const float*)d_in[18];
    const float* m_cb  = (const float*)d_in[19];
    const float* m_xW  = (const float*)d_in[20];
    const float* m_dtW = (const float*)d_in[21];
    const float* m_dtb = (const float*)d_in[22];
    const float* m_Al  = (const float*)d_in[23];
    const float* m_D   = (const float*)d_in[24];
    const float* m_oW  = (const float*)d_in[25];
    const float* p_W1  = (const float*)d_in[26];
    const float* p_b1  = (const float*)d_in[27];
    const float* p_W2  = (const float*)d_in[28];
    const float* p_b2  = (const float*)d_in[29];
    const float* bn1w = (const float*)d_in[30];
    const float* bn1b = (const float*)d_in[31];
    const float* bn2w = (const float*)d_in[32];
    const float* bn2b = (const float*)d_in[33];
    const float* bn3w = (const float*)d_in[34];
    const float* bn3b = (const float*)d_in[35];
    const float* hlw = (const float*)d_in[36];
    const float* hlb = (const float*)d_in[37];
    const float* hW1 = (const float*)d_in[38];
    const float* hb1 = (const float*)d_in[39];
    const float* hbw = (const float*)d_in[40];
    const float* hbb = (const float*)d_in[41];
    const float* hW2 = (const float*)d_in[42];
    const float* hb2 = (const float*)d_in[43];
    float* outp = (float*)d_out;

    char* ws = (char*)d_ws;
    size_t o = 0;
    auto alloc = [&](size_t bytes) { size_t r = o; o += (bytes + 255) & ~(size_t)255; return r; };
    float* X   = (float*)(ws + alloc((size_t)NN * CC * 4));    // 64 MB persistent
    float* H1  = (float*)(ws + alloc((size_t)NN * CC * 4));    // 64 MB GINE out (pre-BN1)
    float* H2O = (float*)(ws + alloc((size_t)NN * CC * 4));    // 64 MB mamba out (pre-BN2)
    float* S1  = (float*)(ws + alloc((size_t)CHR * CC * 4));   // 16 MB chunk scratch
    float* S2  = (float*)(ws + alloc((size_t)CHR * 512 * 4));  // 32 MB chunk scratch
    float* DT  = (float*)(ws + alloc((size_t)CHR * 48 * 4));   // 3 MB
    float* WP  = (float*)(ws + alloc(256 * KPAD * 4));
    float* BP  = (float*)(ws + alloc(256 * 4));
    float* pS  = (float*)(ws + alloc(2 * 256 * 256 * 4));
    float* pQ  = (float*)(ws + alloc(2 * 256 * 256 * 4));
    float* sc1 = (float*)(ws + alloc(256 * 4));
    float* sh1 = (float*)(ws + alloc(256 * 4));
    float* sc2 = (float*)(ws + alloc(256 * 4));
    float* sh2 = (float*)(ws + alloc(256 * 4));
    float* sc3 = (float*)(ws + alloc(256 * 4));
    float* sh3 = (float*)(ws + alloc(256 * 4));
    float* peSc = (float*)(ws + alloc(4 * 4));
    float* peSh = (float*)(ws + alloc(4 * 4));
    float* gm  = (float*)(ws + alloc(GG * 4));
    float* gr  = (float*)(ws + alloc(GG * 4));
    float* hsb = (float*)(ws + alloc(HH * CC * 4));
    float* hqb = (float*)(ws + alloc(HH * CC * 4));
    float* S2lo = S2;                       // [CHR,256]
    float* S2hi = S2 + (size_t)CHR * CC;    // [CHR,256]
    float* pooled = S1;                     // heads
    float* tln    = S1 + (1 << 18);         // 1 MB in
    float* t2b    = S2;

    dim3 B256(256);
    const i64 zero = 0;
    const float* NUL = nullptr;

    // ---- embeddings (chunked) ----
    k_padw<<<dim3(KPAD), B256, 0, stream>>>(node_W, node_b, WP, BP);
    k_pestat<<<dim3(1), B256, 0, stream>>>(pe, pe_bnw, pe_bnb, peSc, peSh);
    for (int ch = 0; ch < NCHUNK; ++ch) {
        const i64 R0 = (i64)ch * CHR;
        k_padx<<<dim3(1024), B256, 0, stream>>>(x + R0 * 173, S2lo);
        gemm_k<<<dim3(CHR / 128, 2, 1), B256, 0, stream>>>(
            S2lo, NUL, KPAD, WP, BP, NUL, 0, X + R0 * CC, CC, CHR, CC, KPAD,
            zero, zero, zero, zero);
    }
    k_peapply<<<dim3(NN / 256), B256, 0, stream>>>(pe, peSc, peSh, pe_W, pe_b, X);

    for (int l = 0; l < LL; ++l) {
        const float* gw1 = gW1 + (i64)l * CC * CC;
        const float* gw2 = gW2 + (i64)l * CC * CC;
        for (int ch = 0; ch < NCHUNK; ++ch) {
            const i64 R0 = (i64)ch * CHR;
            // GINE
            k_gather<<<dim3(2, CHG), dim3(128), 0, stream>>>(X, eidx, eattr, edge_W, edge_b,
                                                             S1, ch * CHG);
            gemm_k<<<dim3(CHR / 128, 2, 1), B256, 0, stream>>>(
                X + R0 * CC, S1, CC, gw1, gb1 + l * CC, NUL, 1, S2lo, CC, CHR, CC, CC,
                zero, zero, zero, zero);
            gemm_k<<<dim3(CHR / 128, 2, 1), B256, 0, stream>>>(
                S2lo, NUL, CC, gw2, gb2 + l * CC, X + R0 * CC, 0, H1 + R0 * CC, CC, CHR, CC, CC,
                zero, zero, zero, zero);
            // Mamba: in_proj (u-half -> S1, z-half -> S2hi)
            gemm_k<<<dim3(CHR / 128, 2, 1), B256, 0, stream>>>(
                X + R0 * CC, NUL, CC, m_inW + (i64)l * 512 * CC, NUL, NUL, 0,
                S1, CC, CHR, CC, CC, zero, zero, zero, zero);
            gemm_k<<<dim3(CHR / 128, 2, 1), B256, 0, stream>>>(
                X + R0 * CC, NUL, CC, m_inW + (i64)l * 512 * CC + (i64)CC * CC, NUL, NUL, 0,
                S2hi, CC, CHR, CC, CC, zero, zero, zero, zero);
            k_conv<<<dim3(1024), B256, 0, stream>>>(S1, m_cW + l * CC * 4, m_cb + l * CC, S2lo);
            gemm_k<<<dim3(CHR / 128, 1, 1), B256, 0, stream>>>(
                S2lo, NUL, CC, m_xW + (i64)l * 48 * CC, NUL, NUL, 0, DT, 48, CHR, 48, CC,
                zero, zero, zero, zero);
            k_scan<<<dim3(CHG), B256, 0, stream>>>(S2lo, DT, m_dtW + (i64)l * CC * 16,
                                                   m_dtb + l * CC, m_Al + (i64)l * CC * 16,
                                                   m_D + l * CC);
            k_gate<<<dim3(1024), B256, 0, stream>>>(S2lo, S2hi);
            gemm_k<<<dim3(CHR / 128, 2, 1), B256, 0, stream>>>(
                S2lo, NUL, CC, m_oW + (i64)l * CC * CC, NUL, X + R0 * CC, 0,
                H2O + R0 * CC, CC, CHR, CC, CC, zero, zero, zero, zero);
        }
        // BN1 + BN2 scale/shift
        k_statpart<<<dim3(256, 2), B256, 0, stream>>>(H1, H2O, pS, pQ);
        k_statred<<<dim3(1), B256, 0, stream>>>(pS, pQ, bn1w + l * CC, bn1b + l * CC, sc1, sh1, 1.f / NN);
        k_statred<<<dim3(1), B256, 0, stream>>>(pS + 65536, pQ + 65536, bn2w + l * CC, bn2b + l * CC,
                                                sc2, sh2, 1.f / NN);
        // mix + MLP (chunked, result -> H1)
        for (int ch = 0; ch < NCHUNK; ++ch) {
            const i64 R0 = (i64)ch * CHR;
            k_mix<<<dim3(1024), B256, 0, stream>>>(H1 + R0 * CC, H2O + R0 * CC,
                                                   sc1, sh1, sc2, sh2, S1);
            gemm_k<<<dim3(CHR / 128, 4, 1), B256, 0, stream>>>(
                S1, NUL, CC, p_W1 + (i64)l * 512 * CC, p_b1 + l * 512, NUL, 1,
                S2, 512, CHR, 512, CC, zero, zero, zero, zero);
            gemm_k<<<dim3(CHR / 128, 2, 1), B256, 0, stream>>>(
                S2, NUL, 512, p_W2 + (i64)l * CC * 512, p_b2 + l * CC, S1, 0,
                H1 + R0 * CC, CC, CHR, CC, 512, zero, zero, zero, zero);
        }
        // BN3 -> X
        k_statpart<<<dim3(256, 1), B256, 0, stream>>>(H1, NUL, pS, pQ);
        k_statred<<<dim3(1), B256, 0, stream>>>(pS, pQ, bn3w + l * CC, bn3b + l * CC, sc3, sh3, 1.f / NN);
        k_affine<<<dim3(2048), B256, 0, stream>>>(H1, sc3, sh3, X);
    }

    // ---- heads ----
    k_pool<<<dim3(GG), B256, 0, stream>>>(X, pooled);
    k_gstat<<<dim3(GG), B256, 0, stream>>>(pooled, gm, gr);
    k_tln<<<dim3(HH * GG), B256, 0, stream>>>(pooled, gm, gr, hlw, hlb, tln);
    gemm_k<<<dim3(GG / 128, 2, HH), B256, 0, stream>>>(
        tln, NUL, CC, hW1, hb1, NUL, 0, t2b, CC, GG, CC, CC,
        (i64)GG * CC, (i64)CC * CC, (i64)CC, (i64)GG * CC);
    k_hstat<<<dim3(HH), B256, 0, stream>>>(t2b, hsb, hqb);
    k_final<<<dim3(GG, HH), dim3(64), 0, stream>>>(t2b, hsb, hqb, hbw, hbb, hW2, hb2, outp);
}
// r10: resubmit after repeated ENOSPC/SIGBUS (environment-side); source-hash bump